// Round 6
// baseline (219.622 us; speedup 1.0000x reference)
//
#include <hip/hip_runtime.h>
#include <cstdint>
#include <cstddef>

// Problem constants (match reference)
#define BB    64
#define TB    2000
#define KB    256
#define NSCB  32       // scan blocks, 2 batches each (512 threads)
#define WPB   125      // lse waves per batch
#define RPW   16       // rows per lse wave  (125*16 = 2000)
#define NLSEB 1000     // lse blocks (8 waves each): 64*125/8

constexpr float LOG2E = 1.4426950408889634f;
constexpr float LN2f  = 0.6931471805599453f;
constexpr float WBF   = 0.36787944117144233f;   // exp(-1) = blank weight (hat domain)

__device__ __forceinline__ float exp2i(int k) {  // exact 2^k, k in [-126, 127]
  return __uint_as_float((uint32_t)(127 + k) << 23);
}
// lane i <- lane i-1 (lane 0 <- 0): DPP wave_shr:1, pure VALU
__device__ __forceinline__ float shr1z(float v) {
  return __int_as_float(__builtin_amdgcn_update_dpp(
      0, __float_as_int(v), 0x138, 0xF, 0xF, true));
}
// wave64 max, pure-VALU DPP tree; uniform result via readlane(63).
__device__ __forceinline__ float dmax64(float v) {
#define DSTEP(ctrl, rm, bc)                                                  \
  { float t = __int_as_float(__builtin_amdgcn_update_dpp(                    \
        __float_as_int(v), __float_as_int(v), (ctrl), (rm), 0xF, (bc)));     \
    v = fmaxf(v, t); }
  DSTEP(0x111, 0xF, true)   // row_shr:1
  DSTEP(0x112, 0xF, true)   // row_shr:2
  DSTEP(0x114, 0xF, true)   // row_shr:4
  DSTEP(0x118, 0xF, true)   // row_shr:8
  DSTEP(0x142, 0xA, false)  // row_bcast:15 -> rows 1,3
  DSTEP(0x143, 0xC, false)  // row_bcast:31 -> rows 2,3
#undef DSTEP
  return __int_as_float(__builtin_amdgcn_readlane(__float_as_int(v), 63));
}
// wave64 sum, pure-VALU DPP tree; total valid in lane 63.
__device__ __forceinline__ float dsum64(float v) {
#define DSTEP(ctrl, rm, bc)                                                  \
  { float t = __int_as_float(__builtin_amdgcn_update_dpp(                    \
        __float_as_int(v), __float_as_int(v), (ctrl), (rm), 0xF, (bc)));     \
    v += t; }
  DSTEP(0x111, 0xF, true) DSTEP(0x112, 0xF, true) DSTEP(0x114, 0xF, true)
  DSTEP(0x118, 0xF, true) DSTEP(0x142, 0xA, false) DSTEP(0x143, 0xC, false)
#undef DSTEP
  return v;
}
__device__ __forceinline__ float wsum64(float v) {
#pragma unroll
  for (int m = 32; m >= 1; m >>= 1) v += __shfl_xor(v, m, 64);
  return v;
}

typedef const __attribute__((address_space(1))) unsigned int* gas1p;
typedef __attribute__((address_space(3))) unsigned int* las3p;

// ---------------------------------------------------------------------------
// blocks [0,32): TWO per-batch scans per block (waves 0-3 batch 2i, waves 4-7
//   batch 2i+1) -> 2 waves/SIMD so stalls of one batch fill from the other.
//   - per group: 4 waves, 2 pairs/lane, 64-pair halo, 1 barrier / 32 steps
//   - emit rows double-buffered in LDS via global_load_lds width-16
//   - LDS reads software-pipelined one 8-group ahead (e/f register sets)
//   - cross-lane ops are ALL DPP (VALU): no lgkm traffic in steady state
//   - stale exact power-of-2 rescale, applied 8 steps after measurement
// blocks >= 32: masked row log-sum-exp, 16 rows per wave (8 waves/block).
// ---------------------------------------------------------------------------
__global__ __launch_bounds__(512)
void fsl_main(const float* __restrict__ x, const int* __restrict__ key_lens,
              const int* __restrict__ query_lens, float* __restrict__ partial,
              float* __restrict__ alast, float* __restrict__ aprev) {
  __shared__ __align__(16) char sbuf[2 * 2 * 32768];  // [group][parity][32KB]
  __shared__ float4 sP4[2][2][128];                   // halo export
  __shared__ int    sC[2][2][4];
  __shared__ float  res2[2][2];

  const int tid512 = threadIdx.x;
  if (blockIdx.x < NSCB) {
    const int g    = tid512 >> 8;        // batch group 0/1
    const int tid  = tid512 & 255;
    const int lane = tid & 63;
    const int w    = tid >> 6;           // wave within group
    const int b    = blockIdx.x * 2 + g;
    const int kl   = key_lens[b];
    const int q0   = query_lens[blockIdx.x * 2];
    const int q1   = query_lens[blockIdx.x * 2 + 1];
    const int qlen = g ? q1 : q0;
    const int p0   = 64 * w - 64 + 2 * lane;   // first owned/halo pair
    const int p1   = p0 + 1;
    const float* xb  = x + (size_t)b * (TB * KB);
    const char*  xbc = (const char*)xb;
    const int  c0cl  = max(0, min(p0, KB - 2));
    const int  col4  = c0cl * 4;
    const size_t lane16 = (size_t)lane * 16;

    const float bias0 = (p0 >= 0 && p0 < kl) ? 0.f : -20000.f;
    const float bias1 = (p1 >= 0 && p1 < kl) ? 0.f : -20000.f;

    float a0 = 0.f, b0 = 0.f, a1 = 0.f, b1 = 0.f, s512 = 0.f;
    int Cw = 0;
    if (p0 == 0) { a0 = WBF; b0 = __builtin_amdgcn_exp2f(LOG2E * xb[0]); }
    float m_red;
    { float ml = fmaxf(fmaxf(a0, b0), fmaxf(a1, b1));
      ml = fmaxf(ml, s512);
      m_red = dmax64(ml); }

    float2 e0, e1, e2, e3, e4, e5, e6, e7;
    float2 f0, f1, f2, f3, f4, f5, f6, f7;

#define STAGE(cc) do {                                                       \
    char* ldsb = sbuf + (g << 16) + (((cc) & 1) << 15) + (w << 13);          \
    const int rr = 1 + 32 * (cc) + (w << 3);                                 \
    _Pragma("unroll")                                                        \
    for (int j = 0; j < 8; ++j) {                                            \
      const int gr = min(rr + j, TB - 1);                                    \
      __builtin_amdgcn_global_load_lds(                                      \
          (gas1p)(const void*)(xbc + (size_t)gr * 1024 + lane16),            \
          (las3p)(void*)(ldsb + (j << 10)), 16, 0, 0);                       \
    }                                                                        \
  } while (0)

#define LOADE(B) do {                                                        \
    e0 = *(const float2*)(dspc + (((B)+0) << 10));                           \
    e1 = *(const float2*)(dspc + (((B)+1) << 10));                           \
    e2 = *(const float2*)(dspc + (((B)+2) << 10));                           \
    e3 = *(const float2*)(dspc + (((B)+3) << 10));                           \
    e4 = *(const float2*)(dspc + (((B)+4) << 10));                           \
    e5 = *(const float2*)(dspc + (((B)+5) << 10));                           \
    e6 = *(const float2*)(dspc + (((B)+6) << 10));                           \
    e7 = *(const float2*)(dspc + (((B)+7) << 10));                           \
  } while (0)
#define LOADF(B) do {                                                        \
    f0 = *(const float2*)(dspc + (((B)+0) << 10));                           \
    f1 = *(const float2*)(dspc + (((B)+1) << 10));                           \
    f2 = *(const float2*)(dspc + (((B)+2) << 10));                           \
    f3 = *(const float2*)(dspc + (((B)+3) << 10));                           \
    f4 = *(const float2*)(dspc + (((B)+4) << 10));                           \
    f5 = *(const float2*)(dspc + (((B)+5) << 10));                           \
    f6 = *(const float2*)(dspc + (((B)+6) << 10));                           \
    f7 = *(const float2*)(dspc + (((B)+7) << 10));                           \
  } while (0)

#define STEPF(EJ, J) do {                                                    \
    const float pm1 = shr1z(b1);                                             \
    const float w0k = __builtin_amdgcn_exp2f(fmaf(EJ.x, LOG2E, bias0));      \
    const float w1k = __builtin_amdgcn_exp2f(fmaf(EJ.y, LOG2E, bias1));      \
    const float t0 = a0 + pm1;                                               \
    const float t1 = a1 + b0;                                                \
    const float nb0 = (b0 + t0) * w0k;                                       \
    const float nb1 = (b1 + t1) * w1k;                                       \
    s512 = (s512 + b1) * WBF;                                                \
    a0 = t0 * WBF; a1 = t1 * WBF; b0 = nb0; b1 = nb1;                        \
  } while (0)

#define STEPG(EJ, J) do {                                                    \
    const float pm1 = shr1z(b1);                                             \
    const float w0k = __builtin_amdgcn_exp2f(fmaf(EJ.x, LOG2E, bias0));      \
    const float w1k = __builtin_amdgcn_exp2f(fmaf(EJ.y, LOG2E, bias1));      \
    const float t0 = a0 + pm1;                                               \
    const float t1 = a1 + b0;                                                \
    const float nb0 = (b0 + t0) * w0k;                                       \
    const float nb1 = (b1 + t1) * w1k;                                       \
    const float ns  = (s512 + b1) * WBF;                                     \
    const bool lv = (J) < rem;                                               \
    a0 = lv ? t0 * WBF : a0; a1 = lv ? t1 * WBF : a1;                        \
    b0 = lv ? nb0 : b0;      b1 = lv ? nb1 : b1;                             \
    s512 = lv ? ns : s512;                                                   \
  } while (0)

#define RUNE(S, B) do { S(e0,0); S(e1,1); S(e2,2); S(e3,3);                  \
                        S(e4,4); S(e5,5); S(e6,6); S(e7,7); } while (0)
#define RUNF(S, B) do { S(f0,(B)+0-(B)+8); S(f1,9); S(f2,10); S(f3,11);      \
                        S(f4,12); S(f5,13); S(f6,14); S(f7,15); } while (0)

#define APPLY() do {                                                         \
    int e = (int)((__float_as_uint(m_red) >> 23) & 0xFF) - 127;              \
    e = (m_red > 0.f) ? e : 0;                                               \
    const float sc = exp2i(-e);                                              \
    a0 *= sc; b0 *= sc; a1 *= sc; b1 *= sc; s512 *= sc; Cw += e;             \
  } while (0)
#define MEASURE() do {                                                       \
    float ml = fmaxf(fmaxf(a0, b0), fmaxf(a1, b1));                          \
    ml = fmaxf(ml, s512);                                                    \
    m_red = dmax64(ml);                                                      \
  } while (0)

#define SYNC(cc) do {                                                        \
    APPLY();                                                                 \
    if (lane >= 32) sP4[g][(cc) & 1][32 * w - 32 + lane] =                   \
        make_float4(a0, b0, a1, b1);                                         \
    if (lane == 32) sC[g][(cc) & 1][w] = Cw;                                 \
    __syncthreads();                                                         \
    const int Cl = (w > 0) ? sC[g][(cc) & 1][w - 1] : Cw;                    \
    const int d = Cl - Cw;                                                   \
    if (d > 0) {            /* adopt larger left scale: never overflow */    \
      const int dcn = min(d, 252), dh = dcn >> 1;                            \
      const float s1 = exp2i(-dh), s2 = exp2i(-(dcn - dh));                  \
      a0 = a0*s1*s2; b0 = b0*s1*s2; a1 = a1*s1*s2; b1 = b1*s1*s2;            \
      s512 = s512*s1*s2; Cw = Cl;                                            \
    }                                                                        \
    if (w > 0 && lane < 32) {                                                \
      const float4 v = sP4[g][(cc) & 1][32 * w - 32 + lane];                 \
      const int dc = max(min(d, 0), -252); const int dh2 = dc >> 1;          \
      const float fa = exp2i(dh2), fb = exp2i(dc - dh2);                     \
      a0 = v.x*fa*fb; b0 = v.y*fa*fb; a1 = v.z*fa*fb; b1 = v.w*fa*fb;        \
    }                                                                        \
    MEASURE();                                                               \
  } while (0)

    const int myTOT  = qlen - 1;                 // live steps t = 1..qlen-1
    const int TOTmax = max(q0, q1) - 1;
    const int NCH    = (TOTmax + 31) >> 5;       // chunks (block-uniform)

    STAGE(0);
    __syncthreads();                             // publishes buf parity 0

    for (int c = 0; c < NCH; ++c) {
      if (c + 1 < NCH) STAGE(c + 1);
      const char* dspc = sbuf + (g << 16) + ((c & 1) << 15) + col4;
      LOADE(0); LOADF(8);
      if (myTOT >= 32 * c + 32) {                // fully-live chunk
        RUNE(STEPF, 0);  APPLY(); MEASURE(); LOADE(16);
        RUNF(STEPF, 8);  APPLY(); MEASURE(); LOADF(24);
        RUNE(STEPF, 16); APPLY(); MEASURE();
        RUNF(STEPF, 24);
      } else {                                   // guarded (possibly dead)
        const int rem = myTOT - 32 * c;          // live j < rem
        RUNE(STEPG, 0);  APPLY(); MEASURE(); LOADE(16);
        RUNF(STEPG, 8);  APPLY(); MEASURE(); LOADF(24);
        RUNE(STEPG, 16); APPLY(); MEASURE();
        RUNF(STEPG, 24);
      }
      SYNC(c);
    }
#undef STAGE
#undef LOADE
#undef LOADF
#undef STEPF
#undef STEPG
#undef RUNE
#undef RUNF
#undef APPLY
#undef MEASURE
#undef SYNC

    // readout: a_last = state 2*kl, a_prev = state 2*kl-1 (owned lanes only)
    const float fC = (float)Cw;
    if (lane >= 32) {
      if (p0 == kl)     res2[g][0] = log2f(a0) + fC;
      if (p1 == kl)     res2[g][0] = log2f(a1) + fC;
      if (p0 == kl - 1) res2[g][1] = log2f(b0) + fC;
      if (p1 == kl - 1) res2[g][1] = log2f(b1) + fC;
    }
    if (w == 3 && lane == 63 && kl == 256) {
      res2[g][0] = log2f(s512) + fC;
      res2[g][1] = log2f(b1) + fC;    // pair 255 odd = state 511
    }
    __syncthreads();
    if (tid == 0) { alast[b] = res2[g][0] * LN2f; aprev[b] = res2[g][1] * LN2f; }

  } else {
    // -------- lse row partials: 16 rows/wave, DPP sum, no max pass --------
    const int gwid = (blockIdx.x - NSCB) * 8 + (tid512 >> 6);  // [0,8000)
    const int lane = tid512 & 63;
    const int b    = gwid / WPB;
    const int widx = gwid - b * WPB;
    const int kl   = key_lens[b];
    const int qlen = query_lens[b];
    const float* xb = x + (size_t)b * (TB * KB);
    const int c0 = lane * 4;
    const float bA = (c0 + 0 < kl) ? 0.f : -20000.f;
    const float bBv= (c0 + 1 < kl) ? 0.f : -20000.f;
    const float bC = (c0 + 2 < kl) ? 0.f : -20000.f;
    const float bD = (c0 + 3 < kl) ? 0.f : -20000.f;
    float acc = 0.f;
    const int tbase = widx * RPW;
#pragma unroll 4
    for (int k = 0; k < RPW; ++k) {
      const int t = tbase + k;
      const float4 v = *(const float4*)(xb + (size_t)t * KB + c0);
      float s = __builtin_amdgcn_exp2f(fmaf(v.x, LOG2E, bA))
              + __builtin_amdgcn_exp2f(fmaf(v.y, LOG2E, bBv))
              + __builtin_amdgcn_exp2f(fmaf(v.z, LOG2E, bC))
              + __builtin_amdgcn_exp2f(fmaf(v.w, LOG2E, bD));
      s = dsum64(s);                             // total in lane 63
      s += WBF;                                  // blank term exp(-1)
      const float l2 = __builtin_amdgcn_logf(s); // log2(s)
      acc += (t < qlen) ? l2 : 0.f;
    }
    if (lane == 63) partial[gwid] = acc * LN2f;
  }
}

// ---------------------------------------------------------------------------
// finish: per-batch SumLse + loss + mean, one block.
// ---------------------------------------------------------------------------
__global__ __launch_bounds__(256)
void fsl_finish(const float* __restrict__ partial, const int* __restrict__ key_lens,
                const float* __restrict__ alast, const float* __restrict__ aprev,
                float* __restrict__ out) {
  const int tid = threadIdx.x;
  const int b = tid >> 2, q = tid & 3;
  float s = 0.f;
  for (int j = q; j < WPB; j += 4) s += partial[b * WPB + j];
  s += __shfl_xor(s, 1, 64);
  s += __shfl_xor(s, 2, 64);
  float lossb = 0.f;
  if (q == 0) {
    const float SumLse = s;
    const float al = alast[b], ap = aprev[b];
    const float mx = fmaxf(al, ap);
    const float lae = (mx == -INFINITY) ? -INFINITY
                                        : mx + log1pf(expf(-fabsf(al - ap)));
    const float nll = SumLse - lae;
    const int kl = key_lens[b];
    float lv = nll / (float)max(kl, 1);
    if (nll > 5e29f) lv = 0.f;
    lossb = lv;
  }
  float v = wsum64(lossb);
  __shared__ float sm[4];
  if ((tid & 63) == 0) sm[tid >> 6] = v;
  __syncthreads();
  if (tid == 0) out[0] = ((sm[0] + sm[1]) + (sm[2] + sm[3])) * (1.0f / 64.0f);
}

extern "C" void kernel_launch(void* const* d_in, const int* in_sizes, int n_in,
                              void* d_out, int out_size, void* d_ws, size_t ws_size,
                              hipStream_t stream) {
  const float* x     = (const float*)d_in[0];
  const int*   klens = (const int*)d_in[1];
  const int*   qlens = (const int*)d_in[2];
  float* out = (float*)d_out;

  float* partial = (float*)d_ws;            // BB*WPB = 8000 floats
  float* alast   = partial + BB * WPB;      // 64
  float* aprev   = alast + BB;              // 64

  fsl_main  <<<NSCB + NLSEB, 512, 0, stream>>>(x, klens, qlens, partial, alast, aprev);
  fsl_finish<<<1, 256, 0, stream>>>(partial, klens, alast, aprev, out);
}

// Round 7
// 181.821 us; speedup vs baseline: 1.2079x; 1.2079x over previous
//
#include <hip/hip_runtime.h>
#include <cstdint>
#include <cstddef>

// Problem constants (match reference)
#define BB    64
#define TB    2000
#define KB    256
#define WPB   125      // lse wave-jobs per batch
#define RPW   16       // rows per lse wave-job (125*16 = 2000)
#define NLSEB 2000     // lse blocks (4 waves each): 64*125/4

constexpr float LOG2E = 1.4426950408889634f;
constexpr float LN2f  = 0.6931471805599453f;
constexpr float WBF   = 0.36787944117144233f;   // exp(-1)

__device__ __forceinline__ float exp2i(int k) {  // exact 2^k, k in [-126,127]
  return __uint_as_float((uint32_t)(127 + k) << 23);
}
// lane i <- lane i-1 (lane 0 <- 0): DPP wave_shr:1, pure VALU (validated r5/r6)
__device__ __forceinline__ float shr1z(float v) {
  return __int_as_float(__builtin_amdgcn_update_dpp(
      0, __float_as_int(v), 0x138, 0xF, 0xF, true));
}
// wave64 max, pure-VALU DPP tree (validated r6); uniform via readlane(63)
__device__ __forceinline__ float dmax64(float v) {
#define DSTEP(ctrl, rm, bc)                                                  \
  { float t = __int_as_float(__builtin_amdgcn_update_dpp(                    \
        __float_as_int(v), __float_as_int(v), (ctrl), (rm), 0xF, (bc)));     \
    v = fmaxf(v, t); }
  DSTEP(0x111, 0xF, true) DSTEP(0x112, 0xF, true) DSTEP(0x114, 0xF, true)
  DSTEP(0x118, 0xF, true) DSTEP(0x142, 0xA, false) DSTEP(0x143, 0xC, false)
#undef DSTEP
  return __int_as_float(__builtin_amdgcn_readlane(__float_as_int(v), 63));
}
// wave64 sum, pure-VALU DPP tree; total valid in lane 63 (validated r6)
__device__ __forceinline__ float dsum64(float v) {
#define DSTEP(ctrl, rm, bc)                                                  \
  { float t = __int_as_float(__builtin_amdgcn_update_dpp(                    \
        __float_as_int(v), __float_as_int(v), (ctrl), (rm), 0xF, (bc)));     \
    v += t; }
  DSTEP(0x111, 0xF, true) DSTEP(0x112, 0xF, true) DSTEP(0x114, 0xF, true)
  DSTEP(0x118, 0xF, true) DSTEP(0x142, 0xA, false) DSTEP(0x143, 0xC, false)
#undef DSTEP
  return v;
}
__device__ __forceinline__ float wsum64(float v) {
#pragma unroll
  for (int m = 32; m >= 1; m >>= 1) v += __shfl_xor(v, m, 64);
  return v;
}

typedef const __attribute__((address_space(1))) unsigned int* gas1p;
typedef __attribute__((address_space(3))) unsigned int* las3p;

// ---------------------------------------------------------------------------
// blocks [0,64): single-wave CTC scan (wave 0) + 3 producer waves.
//   - wave 0: 4 pairs/lane (513 states), 1 DPP shift/step, ZERO barriers
//   - waves 1-3: stream emit rows into an 8-group (64-row) LDS ring via
//     global_load_lds; publish progress via LDS flags after vmcnt drain
//   - e^1-fold: evens have NO multiply; readout subtracts (qlen-1)
//   - stale-by-8 exact power-of-2 rescale, normalized to 2^-24
// blocks >= 64: masked row log-sum-exp, 16 rows per wave, DPP sum.
// ---------------------------------------------------------------------------
__global__ __launch_bounds__(256)
void fsl_main(const float* __restrict__ x, const int* __restrict__ key_lens,
              const int* __restrict__ query_lens, float* __restrict__ partial,
              float* __restrict__ alast, float* __restrict__ aprev) {
  __shared__ __align__(16) char ring[86016];   // 64KB ring + pad -> 1 block/CU
  __shared__ int prodG[3];                     // per-producer: my groups < v staged
  __shared__ int consG;                        // groups < v consumed (reg-loaded)

  const int tid = threadIdx.x;
  if (blockIdx.x < BB) {
    const int b    = blockIdx.x;
    const int lane = tid & 63;
    const int w    = tid >> 6;
    const int kl   = key_lens[b];
    const int qlen = query_lens[b];
    const int total = qlen - 1;                // steps t = 1..total (all live)
    const int ng    = (total + 7) >> 3;        // 8-step groups
    const float* xb  = x + (size_t)b * (TB * KB);
    const char*  xbc = (const char*)xb;
    const int lane16 = lane << 4;

    if (tid == 0) { prodG[0] = 0; prodG[1] = 0; prodG[2] = 0; consG = 0; }
    __syncthreads();                           // the ONLY barrier

    if (w == 0) {
      // =================== consumer: the scan wave ===================
      const int pbase = lane << 2;             // first pair owned
      const float bias0 = (pbase + 0 < kl) ? LOG2E : -20000.f;
      const float bias1 = (pbase + 1 < kl) ? LOG2E : -20000.f;
      const float bias2 = (pbase + 2 < kl) ? LOG2E : -20000.f;
      const float bias3 = (pbase + 3 < kl) ? LOG2E : -20000.f;

      float a0 = 0.f, a1 = 0.f, a2 = 0.f, a3 = 0.f;
      float b0 = 0.f, b1 = 0.f, b2 = 0.f, b3 = 0.f, s512 = 0.f;
      const float x00 = xb[0];
      if (lane == 0) { a0 = WBF; b0 = __builtin_amdgcn_exp2f(x00 * LOG2E); }
      int Cw = 0;
      float m_red = dmax64(fmaxf(a0, b0));

      float4 e0, e1, e2, e3, e4, e5, e6, e7;
      float4 f0, f1, f2, f3, f4, f5, f6, f7;
      volatile int* vp0 = &prodG[0];
      volatile int* vp1 = &prodG[1];
      volatile int* vp2 = &prodG[2];

#define POLL(GN) do {                                                        \
    const int tgt_ = (GN);                                                   \
    int c0_ = *vp0, c1_ = *vp1, c2_ = *vp2;                                  \
    while (min(c0_, min(c1_, c2_)) < tgt_) {                                 \
      __builtin_amdgcn_s_sleep(2);                                           \
      c0_ = *vp0; c1_ = *vp1; c2_ = *vp2;                                    \
    }                                                                        \
    __asm__ __volatile__("" ::: "memory");                                   \
  } while (0)

#define LD8(E, g) do {                                                       \
    const char* sb_ = ring + (((g) & 7) << 13) + lane16;                     \
    E##0 = *(const float4*)(sb_);                                            \
    E##1 = *(const float4*)(sb_ + 1024);                                     \
    E##2 = *(const float4*)(sb_ + 2048);                                     \
    E##3 = *(const float4*)(sb_ + 3072);                                     \
    E##4 = *(const float4*)(sb_ + 4096);                                     \
    E##5 = *(const float4*)(sb_ + 5120);                                     \
    E##6 = *(const float4*)(sb_ + 6144);                                     \
    E##7 = *(const float4*)(sb_ + 7168);                                     \
  } while (0)

#define STEP1(EV) do {                                                       \
    const float pm1 = shr1z(b3);                                             \
    const float w0_ = __builtin_amdgcn_exp2f(fmaf(EV.x, LOG2E, bias0));      \
    const float w1_ = __builtin_amdgcn_exp2f(fmaf(EV.y, LOG2E, bias1));      \
    const float w2_ = __builtin_amdgcn_exp2f(fmaf(EV.z, LOG2E, bias2));      \
    const float w3_ = __builtin_amdgcn_exp2f(fmaf(EV.w, LOG2E, bias3));      \
    const float t0_ = a0 + pm1;                                              \
    const float t1_ = a1 + b0;                                               \
    const float t2_ = a2 + b1;                                               \
    const float t3_ = a3 + b2;                                               \
    s512 = s512 + b3;                                                        \
    b0 = (b0 + t0_) * w0_;                                                   \
    b1 = (b1 + t1_) * w1_;                                                   \
    b2 = (b2 + t2_) * w2_;                                                   \
    b3 = (b3 + t3_) * w3_;                                                   \
    a0 = t0_; a1 = t1_; a2 = t2_; a3 = t3_;                                  \
  } while (0)

#define STEP1G(EV, J) do { if ((J) < rem) { STEP1(EV); } } while (0)

#define RUN8(E)  do { STEP1(E##0); STEP1(E##1); STEP1(E##2); STEP1(E##3);    \
                      STEP1(E##4); STEP1(E##5); STEP1(E##6); STEP1(E##7); } while (0)
#define RUN8G(E) do { STEP1G(E##0,0); STEP1G(E##1,1); STEP1G(E##2,2);        \
                      STEP1G(E##3,3); STEP1G(E##4,4); STEP1G(E##5,5);        \
                      STEP1G(E##6,6); STEP1G(E##7,7); } while (0)

#define APPLY() do {                                                         \
    int e_ = (int)((__float_as_uint(m_red) >> 23) & 0xFF) - 127;             \
    if (!(m_red > 0.f)) e_ = -24;                                            \
    const int k_ = e_ + 24;              /* normalize max to 2^-24 */        \
    if (k_ > 126) {                                                          \
      const int kh_ = k_ >> 1;                                               \
      const float s1_ = exp2i(-kh_), s2_ = exp2i(-(k_ - kh_));               \
      a0 *= s1_; a1 *= s1_; a2 *= s1_; a3 *= s1_;                            \
      b0 *= s1_; b1 *= s1_; b2 *= s1_; b3 *= s1_; s512 *= s1_;               \
      a0 *= s2_; a1 *= s2_; a2 *= s2_; a3 *= s2_;                            \
      b0 *= s2_; b1 *= s2_; b2 *= s2_; b3 *= s2_; s512 *= s2_;               \
    } else {                                                                 \
      const float s_ = exp2i(-k_);                                           \
      a0 *= s_; a1 *= s_; a2 *= s_; a3 *= s_;                                \
      b0 *= s_; b1 *= s_; b2 *= s_; b3 *= s_; s512 *= s_;                    \
    }                                                                        \
    Cw += k_;                                                                \
  } while (0)

#define MEASURE() do {                                                       \
    float ml_ = fmaxf(fmaxf(fmaxf(a0, a1), fmaxf(a2, a3)),                   \
                      fmaxf(fmaxf(b0, b1), fmaxf(b2, b3)));                  \
    ml_ = fmaxf(ml_, s512);                                                  \
    m_red = dmax64(ml_);                                                     \
  } while (0)

      POLL(2);
      LD8(e, 0); LD8(f, 1);
      int cg = 0;
      for (;;) {
        if (8 * cg + 8 <= total) { RUN8(e); }
        else { const int rem = total - 8 * cg; RUN8G(e); }
        APPLY(); MEASURE();
        if (cg + 2 < ng) { POLL(cg + 3); LD8(e, cg + 2); }
        if (cg + 1 < ng) {
          if (8 * cg + 16 <= total) { RUN8(f); }
          else { const int rem = total - 8 * cg - 8; RUN8G(f); }
          APPLY(); MEASURE();
        }
        if (cg + 3 < ng) { POLL(cg + 4); LD8(f, cg + 3); }
        __asm__ __volatile__("" ::: "memory");
        if (lane == 0) *(volatile int*)&consG = cg + 4;  // after LD8s retire
        cg += 2;
        if (cg >= ng) break;
      }
#undef POLL
#undef LD8
#undef STEP1
#undef STEP1G
#undef RUN8
#undef RUN8G
#undef APPLY
#undef MEASURE

      // readout (producers are done: consumer consumed through ng)
      float* ev = (float*)ring;
      float* od = (float*)(ring + 4096);
      *(float4*)(ev + (lane << 2)) = make_float4(a0, a1, a2, a3);
      *(float4*)(od + (lane << 2)) = make_float4(b0, b1, b2, b3);
      if (lane == 63) *(float*)(ring + 8192) = s512;
      __asm__ __volatile__("" ::: "memory");
      if (lane == 0) {
        const float aL = (kl < 256) ? ev[kl] : *(float*)(ring + 8192);
        const float aP = od[kl - 1];
        const float base = (float)Cw;
        alast[b] = (log2f(aL) + base) * LN2f - (float)total;
        aprev[b] = (log2f(aP) + base) * LN2f - (float)total;
      }
    } else {
      // =================== producers: waves 1..3 ===================
      const int pw = w - 1;                    // handles groups g % 3 == pw
      volatile int* vc = &consG;
      int mycnt = 0;
      for (int g = pw; g < ng; g += 3) {
        if (g >= 8) {                          // ring slot reuse: need g-8 consumed
          int c_ = *vc;
          while (c_ < g - 7) { __builtin_amdgcn_s_sleep(8); c_ = *vc; }
          __asm__ __volatile__("" ::: "memory");
        }
        char* dstb = ring + ((g & 7) << 13);
        const int rb = 8 * g + 1;
#pragma unroll
        for (int j = 0; j < 8; ++j) {
          if (rb + j <= total)
            __builtin_amdgcn_global_load_lds(
                (gas1p)(const void*)(xbc + (size_t)(rb + j) * 1024 + lane16),
                (las3p)(void*)(dstb + (j << 10)), 16, 0, 0);
        }
        ++mycnt;
        if ((mycnt & 1) == 0 || g + 3 >= ng) { // drain every 2 own groups + last
          __asm__ __volatile__("s_waitcnt vmcnt(0)" ::: "memory");
          if (lane == 0) *(volatile int*)&prodG[pw] = g + 3;
        }
      }
    }

  } else {
    // -------- lse row partials: 16 rows/wave, DPP sum, no max pass --------
    const int gwid = (blockIdx.x - BB) * 4 + (tid >> 6);   // [0, 8000)
    const int lane = tid & 63;
    const int b    = gwid / WPB;
    const int widx = gwid - b * WPB;
    const int kl   = key_lens[b];
    const int qlen = query_lens[b];
    const float* xb = x + (size_t)b * (TB * KB);
    const int c0 = lane * 4;
    const float bA = (c0 + 0 < kl) ? 0.f : -20000.f;
    const float bBv= (c0 + 1 < kl) ? 0.f : -20000.f;
    const float bC = (c0 + 2 < kl) ? 0.f : -20000.f;
    const float bD = (c0 + 3 < kl) ? 0.f : -20000.f;
    float acc = 0.f;
    const int tbase = widx * RPW;
#pragma unroll 4
    for (int k = 0; k < RPW; ++k) {
      const int t = tbase + k;
      const float4 v = *(const float4*)(xb + (size_t)t * KB + c0);
      float s = __builtin_amdgcn_exp2f(fmaf(v.x, LOG2E, bA))
              + __builtin_amdgcn_exp2f(fmaf(v.y, LOG2E, bBv))
              + __builtin_amdgcn_exp2f(fmaf(v.z, LOG2E, bC))
              + __builtin_amdgcn_exp2f(fmaf(v.w, LOG2E, bD));
      s = dsum64(s);                           // total in lane 63
      s += WBF;                                // blank term exp(-1)
      const float l2 = __builtin_amdgcn_logf(s);   // log2(s)
      acc += (t < qlen) ? l2 : 0.f;
    }
    if (lane == 63) partial[gwid] = acc * LN2f;
  }
}

// ---------------------------------------------------------------------------
// finish: per-batch SumLse + loss + mean, one block.
// ---------------------------------------------------------------------------
__global__ __launch_bounds__(256)
void fsl_finish(const float* __restrict__ partial, const int* __restrict__ key_lens,
                const float* __restrict__ alast, const float* __restrict__ aprev,
                float* __restrict__ out) {
  const int tid = threadIdx.x;
  const int b = tid >> 2, q = tid & 3;
  float s = 0.f;
  for (int j = q; j < WPB; j += 4) s += partial[b * WPB + j];
  s += __shfl_xor(s, 1, 64);
  s += __shfl_xor(s, 2, 64);
  float lossb = 0.f;
  if (q == 0) {
    const float SumLse = s;
    const float al = alast[b], ap = aprev[b];
    const float mx = fmaxf(al, ap);
    const float lae = (mx == -INFINITY) ? -INFINITY
                                        : mx + log1pf(expf(-fabsf(al - ap)));
    const float nll = SumLse - lae;
    const int kl = key_lens[b];
    float lv = nll / (float)max(kl, 1);
    if (nll > 5e29f) lv = 0.f;
    lossb = lv;
  }
  float v = wsum64(lossb);
  __shared__ float sm[4];
  if ((tid & 63) == 0) sm[tid >> 6] = v;
  __syncthreads();
  if (tid == 0) out[0] = ((sm[0] + sm[1]) + (sm[2] + sm[3])) * (1.0f / 64.0f);
}

extern "C" void kernel_launch(void* const* d_in, const int* in_sizes, int n_in,
                              void* d_out, int out_size, void* d_ws, size_t ws_size,
                              hipStream_t stream) {
  const float* x     = (const float*)d_in[0];
  const int*   klens = (const int*)d_in[1];
  const int*   qlens = (const int*)d_in[2];
  float* out = (float*)d_out;

  float* partial = (float*)d_ws;            // BB*WPB = 8000 floats
  float* alast   = partial + BB * WPB;      // 64
  float* aprev   = alast + BB;              // 64

  fsl_main  <<<BB + NLSEB, 256, 0, stream>>>(x, klens, qlens, partial, alast, aprev);
  fsl_finish<<<1, 256, 0, stream>>>(partial, klens, alast, aprev, out);
}

// Round 8
// 143.158 us; speedup vs baseline: 1.5341x; 1.2701x over previous
//
#include <hip/hip_runtime.h>
#include <cstdint>
#include <cstddef>

// Problem constants (match reference)
#define BB    64
#define TB    2000
#define KB    256

constexpr float LOG2E = 1.4426950408889634f;
constexpr float LN2f  = 0.6931471805599453f;
constexpr float WBF   = 0.36787944117144233f;   // exp(-1)

__device__ __forceinline__ float exp2i(int k) {  // exact 2^k, k in [-126,127]
  return __uint_as_float((uint32_t)(127 + k) << 23);
}
// lane i <- lane i-1 (lane 0 <- 0): DPP wave_shr:1, pure VALU (validated r4-r7)
__device__ __forceinline__ float shr1z(float v) {
  return __int_as_float(__builtin_amdgcn_update_dpp(
      0, __float_as_int(v), 0x138, 0xF, 0xF, true));
}
// wave64 max, pure-VALU DPP tree (validated r6/r7); uniform via readlane(63)
__device__ __forceinline__ float dmax64(float v) {
#define DSTEP(ctrl, rm, bc)                                                  \
  { float t = __int_as_float(__builtin_amdgcn_update_dpp(                    \
        __float_as_int(v), __float_as_int(v), (ctrl), (rm), 0xF, (bc)));     \
    v = fmaxf(v, t); }
  DSTEP(0x111, 0xF, true) DSTEP(0x112, 0xF, true) DSTEP(0x114, 0xF, true)
  DSTEP(0x118, 0xF, true) DSTEP(0x142, 0xA, false) DSTEP(0x143, 0xC, false)
#undef DSTEP
  return __int_as_float(__builtin_amdgcn_readlane(__float_as_int(v), 63));
}
// wave64 sum, pure-VALU DPP tree; total valid in lane 63 (validated r6/r7)
__device__ __forceinline__ float dsum64(float v) {
#define DSTEP(ctrl, rm, bc)                                                  \
  { float t = __int_as_float(__builtin_amdgcn_update_dpp(                    \
        __float_as_int(v), __float_as_int(v), (ctrl), (rm), 0xF, (bc)));     \
    v += t; }
  DSTEP(0x111, 0xF, true) DSTEP(0x112, 0xF, true) DSTEP(0x114, 0xF, true)
  DSTEP(0x118, 0xF, true) DSTEP(0x142, 0xA, false) DSTEP(0x143, 0xC, false)
#undef DSTEP
  return v;
}
__device__ __forceinline__ float wsum64(float v) {
#pragma unroll
  for (int m = 32; m >= 1; m >>= 1) v += __shfl_xor(v, m, 64);
  return v;
}

// ---------------------------------------------------------------------------
// 64 blocks, one per batch. Wave 0 = consumer scan wave (513 states,
// 4 pairs/lane, 1 DPP shift/step, ZERO transcendentals, ZERO barriers).
// Waves 1-3 = producers: load x rows, compute weight rows
// w = exp2(x*log2e + bias) (bias bakes key-mask + e^1-fold), ds_write to an
// 8-group LDS ring, AND fold the row log-sum-exp out of the same exp2s:
// lse_row = ln((dsum(w) + 1) * e^-1). No second pass over x at all.
// Flag protocol identical to r7 (proven): prodG[pw] = my groups < v staged,
// consG = groups < v consumed; per-wave in-order DS retirement orders
// data-write -> flag-write and data-read -> consG-write.
// ---------------------------------------------------------------------------
__global__ __launch_bounds__(256)
void fsl_main(const float* __restrict__ x, const int* __restrict__ key_lens,
              const int* __restrict__ query_lens, float* __restrict__ partial,
              float* __restrict__ alast, float* __restrict__ aprev) {
  __shared__ __align__(16) char ring[65536];   // 8 groups x 8 rows x 1KB
  __shared__ int prodG[3];
  __shared__ int consG;

  const int tid  = threadIdx.x;
  const int b    = blockIdx.x;
  const int lane = tid & 63;
  const int w    = tid >> 6;
  const int kl   = key_lens[b];
  const int qlen = query_lens[b];
  const int total = qlen - 1;                // live steps t = 1..total
  const int ng    = (total + 7) >> 3;        // 8-step groups
  const float* xb  = x + (size_t)b * (TB * KB);
  const char*  xbc = (const char*)xb;
  const int lane16 = lane << 4;

  if (tid == 0) { prodG[0] = 0; prodG[1] = 0; prodG[2] = 0; consG = 0; }
  __syncthreads();                           // the ONLY barrier

  if (w == 0) {
    // =================== consumer: the scan wave ===================
    float a0 = 0.f, a1 = 0.f, a2 = 0.f, a3 = 0.f;
    float b0 = 0.f, b1 = 0.f, b2 = 0.f, b3 = 0.f, s512 = 0.f;
    if (lane == 0) { a0 = WBF; b0 = __builtin_amdgcn_exp2f(xb[0] * LOG2E); }
    int Cw = 0;
    float m_red = dmax64(fmaxf(a0, b0));

    float4 e0, e1, e2, e3, e4, e5, e6, e7;
    float4 f0, f1, f2, f3, f4, f5, f6, f7;
    volatile int* vp0 = &prodG[0];
    volatile int* vp1 = &prodG[1];
    volatile int* vp2 = &prodG[2];

#define POLL(GN) do {                                                        \
    const int tgt_ = (GN);                                                   \
    int c0_ = *vp0, c1_ = *vp1, c2_ = *vp2;                                  \
    while (min(c0_, min(c1_, c2_)) < tgt_) {                                 \
      __builtin_amdgcn_s_sleep(2);                                           \
      c0_ = *vp0; c1_ = *vp1; c2_ = *vp2;                                    \
    }                                                                        \
    __asm__ __volatile__("" ::: "memory");                                   \
  } while (0)

#define LD8(E, g) do {                                                       \
    const char* sb_ = ring + (((g) & 7) << 13) + lane16;                     \
    E##0 = *(const float4*)(sb_);                                            \
    E##1 = *(const float4*)(sb_ + 1024);                                     \
    E##2 = *(const float4*)(sb_ + 2048);                                     \
    E##3 = *(const float4*)(sb_ + 3072);                                     \
    E##4 = *(const float4*)(sb_ + 4096);                                     \
    E##5 = *(const float4*)(sb_ + 5120);                                     \
    E##6 = *(const float4*)(sb_ + 6144);                                     \
    E##7 = *(const float4*)(sb_ + 7168);                                     \
  } while (0)

    // EV holds the PRECOMPUTED weights for this step (4 odd-state weights)
#define STEP1(EV) do {                                                       \
    const float pm1 = shr1z(b3);                                             \
    const float t0_ = a0 + pm1;                                              \
    const float t1_ = a1 + b0;                                               \
    const float t2_ = a2 + b1;                                               \
    const float t3_ = a3 + b2;                                               \
    s512 = s512 + b3;                                                        \
    b0 = (b0 + t0_) * EV.x;                                                  \
    b1 = (b1 + t1_) * EV.y;                                                  \
    b2 = (b2 + t2_) * EV.z;                                                  \
    b3 = (b3 + t3_) * EV.w;                                                  \
    a0 = t0_; a1 = t1_; a2 = t2_; a3 = t3_;                                  \
  } while (0)

#define STEP1G(EV, J) do { if ((J) < rem) { STEP1(EV); } } while (0)

#define RUN8(E)  do { STEP1(E##0); STEP1(E##1); STEP1(E##2); STEP1(E##3);    \
                      STEP1(E##4); STEP1(E##5); STEP1(E##6); STEP1(E##7); } while (0)
#define RUN8G(E) do { STEP1G(E##0,0); STEP1G(E##1,1); STEP1G(E##2,2);        \
                      STEP1G(E##3,3); STEP1G(E##4,4); STEP1G(E##5,5);        \
                      STEP1G(E##6,6); STEP1G(E##7,7); } while (0)

#define APPLY() do {                                                         \
    int e_ = (int)((__float_as_uint(m_red) >> 23) & 0xFF) - 127;             \
    if (!(m_red > 0.f)) e_ = -24;                                            \
    const int k_ = e_ + 24;              /* normalize max to 2^-24 */        \
    if (k_ > 126) {                                                          \
      const int kh_ = k_ >> 1;                                               \
      const float s1_ = exp2i(-kh_), s2_ = exp2i(-(k_ - kh_));               \
      a0 *= s1_; a1 *= s1_; a2 *= s1_; a3 *= s1_;                            \
      b0 *= s1_; b1 *= s1_; b2 *= s1_; b3 *= s1_; s512 *= s1_;               \
      a0 *= s2_; a1 *= s2_; a2 *= s2_; a3 *= s2_;                            \
      b0 *= s2_; b1 *= s2_; b2 *= s2_; b3 *= s2_; s512 *= s2_;               \
    } else {                                                                 \
      const float s_ = exp2i(-k_);                                           \
      a0 *= s_; a1 *= s_; a2 *= s_; a3 *= s_;                                \
      b0 *= s_; b1 *= s_; b2 *= s_; b3 *= s_; s512 *= s_;                    \
    }                                                                        \
    Cw += k_;                                                                \
  } while (0)

#define MEASURE() do {                                                       \
    float ml_ = fmaxf(fmaxf(fmaxf(a0, a1), fmaxf(a2, a3)),                   \
                      fmaxf(fmaxf(b0, b1), fmaxf(b2, b3)));                  \
    ml_ = fmaxf(ml_, s512);                                                  \
    m_red = dmax64(ml_);                                                     \
  } while (0)

    POLL(2);
    LD8(e, 0); LD8(f, 1);
    int cg = 0;
    for (;;) {
      if (8 * cg + 8 <= total) { RUN8(e); }
      else { const int rem = total - 8 * cg; RUN8G(e); }
      APPLY(); MEASURE();
      if (cg + 2 < ng) { POLL(cg + 3); LD8(e, cg + 2); }
      if (cg + 1 < ng) {
        if (8 * cg + 16 <= total) { RUN8(f); }
        else { const int rem = total - 8 * cg - 8; RUN8G(f); }
        APPLY(); MEASURE();
      }
      if (cg + 3 < ng) { POLL(cg + 4); LD8(f, cg + 3); }
      __asm__ __volatile__("" ::: "memory");
      if (lane == 0) *(volatile int*)&consG = cg + 4;
      cg += 2;
      if (cg >= ng) break;
    }
#undef POLL
#undef LD8
#undef STEP1
#undef STEP1G
#undef RUN8
#undef RUN8G
#undef APPLY
#undef MEASURE

    // readout: a_last = state 2*kl, a_prev = state 2*kl-1
    float* ev = (float*)ring;
    float* od = (float*)(ring + 4096);
    *(float4*)(ev + (lane << 2)) = make_float4(a0, a1, a2, a3);
    *(float4*)(od + (lane << 2)) = make_float4(b0, b1, b2, b3);
    if (lane == 63) *(float*)(ring + 8192) = s512;
    __asm__ __volatile__("" ::: "memory");
    if (lane == 0) {
      const float aL = (kl < 256) ? ev[kl] : *(float*)(ring + 8192);
      const float aP = od[kl - 1];
      const float dC = (float)Cw - (float)total * LOG2E;  // e-fold removal
      alast[b] = (log2f(aL) + dC) * LN2f;
      aprev[b] = (log2f(aP) + dC) * LN2f;
    }
  } else {
    // =================== producers: waves 1..3 ===================
    const int pw = w - 1;                    // handles groups g % 3 == pw
    const int c0 = lane << 2;
    const float bs0 = (c0 + 0 < kl) ? LOG2E : -20000.f;
    const float bs1 = (c0 + 1 < kl) ? LOG2E : -20000.f;
    const float bs2 = (c0 + 2 < kl) ? LOG2E : -20000.f;
    const float bs3 = (c0 + 3 < kl) ? LOG2E : -20000.f;
    volatile int* vc = &consG;
    float acc = 0.f;                         // row-lse partial (log2 units)

    if (pw == 0) {                           // row 0: lse only (not staged)
      const float4 v = *(const float4*)(xbc + lane16);
      float s_ = __builtin_amdgcn_exp2f(fmaf(v.x, LOG2E, bs0))
               + __builtin_amdgcn_exp2f(fmaf(v.y, LOG2E, bs1))
               + __builtin_amdgcn_exp2f(fmaf(v.z, LOG2E, bs2))
               + __builtin_amdgcn_exp2f(fmaf(v.w, LOG2E, bs3));
      s_ = dsum64(s_);
      acc += __builtin_amdgcn_logf((s_ + 1.0f) * WBF);
    }

    float4 A0, A1, A2, A3, A4, A5, A6, A7;
    float4 B0, B1, B2, B3, B4, B5, B6, B7;
    float4 C0, C1, C2, C3, C4, C5, C6, C7;

#define LOADG(P, GG) do {                                                    \
    const int rb_ = 8 * (GG) + 1;                                            \
    P##0 = *(const float4*)(xbc + (size_t)min(rb_ + 0, TB - 1) * 1024 + lane16); \
    P##1 = *(const float4*)(xbc + (size_t)min(rb_ + 1, TB - 1) * 1024 + lane16); \
    P##2 = *(const float4*)(xbc + (size_t)min(rb_ + 2, TB - 1) * 1024 + lane16); \
    P##3 = *(const float4*)(xbc + (size_t)min(rb_ + 3, TB - 1) * 1024 + lane16); \
    P##4 = *(const float4*)(xbc + (size_t)min(rb_ + 4, TB - 1) * 1024 + lane16); \
    P##5 = *(const float4*)(xbc + (size_t)min(rb_ + 5, TB - 1) * 1024 + lane16); \
    P##6 = *(const float4*)(xbc + (size_t)min(rb_ + 6, TB - 1) * 1024 + lane16); \
    P##7 = *(const float4*)(xbc + (size_t)min(rb_ + 7, TB - 1) * 1024 + lane16); \
  } while (0)

#define PR1(V, J) do {                                                       \
    float4 wv_;                                                              \
    wv_.x = __builtin_amdgcn_exp2f(fmaf(V.x, LOG2E, bs0));                   \
    wv_.y = __builtin_amdgcn_exp2f(fmaf(V.y, LOG2E, bs1));                   \
    wv_.z = __builtin_amdgcn_exp2f(fmaf(V.z, LOG2E, bs2));                   \
    wv_.w = __builtin_amdgcn_exp2f(fmaf(V.w, LOG2E, bs3));                   \
    *(float4*)(dstb_ + ((J) << 10)) = wv_;                                   \
    if (rb_ + (J) <= total) {                                                \
      float sr_ = (wv_.x + wv_.y) + (wv_.z + wv_.w);                         \
      sr_ = dsum64(sr_);                                                     \
      acc += __builtin_amdgcn_logf((sr_ + 1.0f) * WBF);                      \
    }                                                                        \
  } while (0)

#define PROC(P, GG) do {                                                     \
    const int rb_ = 8 * (GG) + 1;                                            \
    if ((GG) >= 8) {                        /* ring slot reuse */            \
      int c_ = *vc;                                                          \
      while (c_ < (GG) - 7) { __builtin_amdgcn_s_sleep(2); c_ = *vc; }       \
      __asm__ __volatile__("" ::: "memory");                                 \
    }                                                                        \
    char* dstb_ = ring + (((GG) & 7) << 13) + lane16;                        \
    PR1(P##0, 0); PR1(P##1, 1); PR1(P##2, 2); PR1(P##3, 3);                  \
    PR1(P##4, 4); PR1(P##5, 5); PR1(P##6, 6); PR1(P##7, 7);                  \
    __asm__ __volatile__("s_waitcnt lgkmcnt(0)" ::: "memory");               \
    if (lane == 0) *(volatile int*)&prodG[pw] = (GG) + 3;                    \
  } while (0)

    LOADG(A, pw); LOADG(B, pw + 3);
    int g = pw;
    for (;;) {
      LOADG(C, g + 6);
      PROC(A, g);
      g += 3; if (g >= ng) break;
      LOADG(A, g + 6);
      PROC(B, g);
      g += 3; if (g >= ng) break;
      LOADG(B, g + 6);
      PROC(C, g);
      g += 3; if (g >= ng) break;
    }
#undef LOADG
#undef PR1
#undef PROC
    __asm__ __volatile__("" ::: "memory");
    if (lane == 0) *(volatile int*)&prodG[pw] = 0x7fffffff;
    if (lane == 63) partial[4 * b + pw] = acc;   // log2-units partial
  }
}

// ---------------------------------------------------------------------------
// finish: per-batch SumLse + loss + mean. One wave of 64 threads.
// ---------------------------------------------------------------------------
__global__ __launch_bounds__(64)
void fsl_finish(const float* __restrict__ partial, const int* __restrict__ key_lens,
                const float* __restrict__ alast, const float* __restrict__ aprev,
                float* __restrict__ out) {
  const int b = threadIdx.x;                 // 0..63
  const float SumLse =
      ((partial[4 * b] + partial[4 * b + 1]) + partial[4 * b + 2]) * LN2f;
  const float al = alast[b], ap = aprev[b];
  const float mx = fmaxf(al, ap);
  const float lae = (mx == -INFINITY) ? -INFINITY
                                      : mx + log1pf(expf(-fabsf(al - ap)));
  const float nll = SumLse - lae;
  const int kl = key_lens[b];
  float lv = nll / (float)max(kl, 1);
  if (nll > 5e29f) lv = 0.f;
  float v = wsum64(lv);
  if (b == 0) out[0] = v * (1.0f / 64.0f);
}

extern "C" void kernel_launch(void* const* d_in, const int* in_sizes, int n_in,
                              void* d_out, int out_size, void* d_ws, size_t ws_size,
                              hipStream_t stream) {
  const float* x     = (const float*)d_in[0];
  const int*   klens = (const int*)d_in[1];
  const int*   qlens = (const int*)d_in[2];
  float* out = (float*)d_out;

  float* partial = (float*)d_ws;            // 64*4 floats (3 used per batch)
  float* alast   = partial + BB * 4;        // 64
  float* aprev   = alast + BB;              // 64

  fsl_main  <<<BB, 256, 0, stream>>>(x, klens, qlens, partial, alast, aprev);
  fsl_finish<<<1, 64, 0, stream>>>(partial, klens, alast, aprev, out);
}

// Round 9
// 123.986 us; speedup vs baseline: 1.7713x; 1.1546x over previous
//
#include <hip/hip_runtime.h>
#include <cstdint>
#include <cstddef>

// Problem constants (match reference)
#define BB    64
#define TB    2000
#define KB    256

constexpr float LOG2E = 1.4426950408889634f;
constexpr float LN2f  = 0.6931471805599453f;
constexpr float WBF   = 0.36787944117144233f;   // exp(-1)

__device__ __forceinline__ float exp2i(int k) {  // exact 2^k, k in [-126,127]
  return __uint_as_float((uint32_t)(127 + k) << 23);
}
// lane i <- lane i-1 (lane 0 <- 0): DPP wave_shr:1, pure VALU (validated r4-r8)
__device__ __forceinline__ float shr1z(float v) {
  return __int_as_float(__builtin_amdgcn_update_dpp(
      0, __float_as_int(v), 0x138, 0xF, 0xF, true));
}
// wave64 max, pure-VALU DPP tree (validated r6-r8); uniform via readlane(63)
__device__ __forceinline__ float dmax64(float v) {
#define DSTEP(ctrl, rm, bc)                                                  \
  { float t = __int_as_float(__builtin_amdgcn_update_dpp(                    \
        __float_as_int(v), __float_as_int(v), (ctrl), (rm), 0xF, (bc)));     \
    v = fmaxf(v, t); }
  DSTEP(0x111, 0xF, true) DSTEP(0x112, 0xF, true) DSTEP(0x114, 0xF, true)
  DSTEP(0x118, 0xF, true) DSTEP(0x142, 0xA, false) DSTEP(0x143, 0xC, false)
#undef DSTEP
  return __int_as_float(__builtin_amdgcn_readlane(__float_as_int(v), 63));
}
// wave64 sum, pure-VALU DPP tree; total valid in lane 63 (validated r6-r8)
__device__ __forceinline__ float dsum64(float v) {
#define DSTEP(ctrl, rm, bc)                                                  \
  { float t = __int_as_float(__builtin_amdgcn_update_dpp(                    \
        __float_as_int(v), __float_as_int(v), (ctrl), (rm), 0xF, (bc)));     \
    v += t; }
  DSTEP(0x111, 0xF, true) DSTEP(0x112, 0xF, true) DSTEP(0x114, 0xF, true)
  DSTEP(0x118, 0xF, true) DSTEP(0x142, 0xA, false) DSTEP(0x143, 0xC, false)
#undef DSTEP
  return v;
}
__device__ __forceinline__ float wsum64(float v) {
#pragma unroll
  for (int m = 32; m >= 1; m >>= 1) v += __shfl_xor(v, m, 64);
  return v;
}

// ---------------------------------------------------------------------------
// 64 blocks, one per batch. Wave 0 = consumer scan (513 states, 4 pairs/lane,
// 1 DPP shift/step, zero transcendentals, zero barriers). Waves 1-3 =
// producers: compute weight rows w = exp2(x*log2e + bias) (bias bakes
// key-mask + e^1-fold), ds_write into an 8-group LDS ring, and fold the row
// log-sum-exp from the same exp2s. Single pass over x.
// r9 deltas vs r8: 3-group register buffer -> 1 POLL / 24 steps; flags read
// as ONE ds_read_b128 (int4); spin-first-then-sleep(1); producer sleep 2.
// Flag protocol proven in r7/r8: in-order per-wave DS retirement orders
// data-write -> flag-write and data-read -> consG-write.
// ---------------------------------------------------------------------------
__global__ __launch_bounds__(256)
void fsl_main(const float* __restrict__ x, const int* __restrict__ key_lens,
              const int* __restrict__ query_lens, float* __restrict__ partial,
              float* __restrict__ alast, float* __restrict__ aprev) {
  __shared__ __align__(16) char ring[65536];   // 8 groups x 8 rows x 1KB
  __shared__ __align__(16) int prodG[4];       // 3 flags + pad (one b128 read)
  __shared__ int consG;

  const int tid  = threadIdx.x;
  const int b    = blockIdx.x;
  const int lane = tid & 63;
  const int w    = tid >> 6;
  const int kl   = key_lens[b];
  const int qlen = query_lens[b];
  const int total = qlen - 1;                // live steps t = 1..total
  const int ng    = (total + 7) >> 3;        // 8-step groups (>=125)
  const float* xb  = x + (size_t)b * (TB * KB);
  const char*  xbc = (const char*)xb;
  const int lane16 = lane << 4;

  if (tid == 0) { prodG[0] = 0; prodG[1] = 0; prodG[2] = 0; prodG[3] = 0x7fffffff; consG = 0; }
  __syncthreads();                           // the ONLY barrier

  if (w == 0) {
    // =================== consumer: the scan wave ===================
    float a0 = 0.f, a1 = 0.f, a2 = 0.f, a3 = 0.f;
    float b0 = 0.f, b1 = 0.f, b2 = 0.f, b3 = 0.f, s512 = 0.f;
    if (lane == 0) { a0 = WBF; b0 = __builtin_amdgcn_exp2f(xb[0] * LOG2E); }
    int Cw = 0;
    float m_red = dmax64(fmaxf(a0, b0));

    float4 e0, e1, e2, e3, e4, e5, e6, e7;
    float4 f0, f1, f2, f3, f4, f5, f6, f7;
    float4 g0, g1, g2, g3, g4, g5, g6, g7;

    // one ds_read_b128 of all 3 flags; spin first, sleep(1) after
#define POLL(GN) do {                                                        \
    const int tgt_ = (GN);                                                   \
    for (;;) {                                                               \
      __asm__ __volatile__("" ::: "memory");                                 \
      const int4 fl_ = *(const int4*)prodG;                                  \
      if (min(fl_.x, min(fl_.y, fl_.z)) >= tgt_) break;                      \
      __builtin_amdgcn_s_sleep(1);                                           \
    }                                                                        \
    __asm__ __volatile__("" ::: "memory");                                   \
  } while (0)

#define LD8(E, g) do {                                                       \
    const char* sb_ = ring + (((g) & 7) << 13) + lane16;                     \
    E##0 = *(const float4*)(sb_);                                            \
    E##1 = *(const float4*)(sb_ + 1024);                                     \
    E##2 = *(const float4*)(sb_ + 2048);                                     \
    E##3 = *(const float4*)(sb_ + 3072);                                     \
    E##4 = *(const float4*)(sb_ + 4096);                                     \
    E##5 = *(const float4*)(sb_ + 5120);                                     \
    E##6 = *(const float4*)(sb_ + 6144);                                     \
    E##7 = *(const float4*)(sb_ + 7168);                                     \
  } while (0)

    // EV holds the PRECOMPUTED weights for this step (4 odd-state weights)
#define STEP1(EV) do {                                                       \
    const float pm1 = shr1z(b3);                                             \
    const float t0_ = a0 + pm1;                                              \
    const float t1_ = a1 + b0;                                               \
    const float t2_ = a2 + b1;                                               \
    const float t3_ = a3 + b2;                                               \
    s512 = s512 + b3;                                                        \
    b0 = (b0 + t0_) * EV.x;                                                  \
    b1 = (b1 + t1_) * EV.y;                                                  \
    b2 = (b2 + t2_) * EV.z;                                                  \
    b3 = (b3 + t3_) * EV.w;                                                  \
    a0 = t0_; a1 = t1_; a2 = t2_; a3 = t3_;                                  \
  } while (0)

#define STEP1G(EV, J) do { if ((J) < rem_) { STEP1(EV); } } while (0)

#define RUN8(E)  do { STEP1(E##0); STEP1(E##1); STEP1(E##2); STEP1(E##3);    \
                      STEP1(E##4); STEP1(E##5); STEP1(E##6); STEP1(E##7); } while (0)
#define RUN8G(E, RM) do { const int rem_ = (RM);                             \
                      STEP1G(E##0,0); STEP1G(E##1,1); STEP1G(E##2,2);        \
                      STEP1G(E##3,3); STEP1G(E##4,4); STEP1G(E##5,5);        \
                      STEP1G(E##6,6); STEP1G(E##7,7); } while (0)

#define APPLY() do {                                                         \
    int e_ = (int)((__float_as_uint(m_red) >> 23) & 0xFF) - 127;             \
    if (!(m_red > 0.f)) e_ = -24;                                            \
    const int k_ = e_ + 24;              /* normalize max to 2^-24 */        \
    if (k_ > 126) {                                                          \
      const int kh_ = k_ >> 1;                                               \
      const float s1_ = exp2i(-kh_), s2_ = exp2i(-(k_ - kh_));               \
      a0 *= s1_; a1 *= s1_; a2 *= s1_; a3 *= s1_;                            \
      b0 *= s1_; b1 *= s1_; b2 *= s1_; b3 *= s1_; s512 *= s1_;               \
      a0 *= s2_; a1 *= s2_; a2 *= s2_; a3 *= s2_;                            \
      b0 *= s2_; b1 *= s2_; b2 *= s2_; b3 *= s2_; s512 *= s2_;               \
    } else {                                                                 \
      const float s_ = exp2i(-k_);                                           \
      a0 *= s_; a1 *= s_; a2 *= s_; a3 *= s_;                                \
      b0 *= s_; b1 *= s_; b2 *= s_; b3 *= s_; s512 *= s_;                    \
    }                                                                        \
    Cw += k_;                                                                \
  } while (0)

#define MEASURE() do {                                                       \
    float ml_ = fmaxf(fmaxf(fmaxf(a0, a1), fmaxf(a2, a3)),                   \
                      fmaxf(fmaxf(b0, b1), fmaxf(b2, b3)));                  \
    ml_ = fmaxf(ml_, s512);                                                  \
    m_red = dmax64(ml_);                                                     \
  } while (0)

    // run one group (guarded at the tail); arithmetic identical to r8
#define RUNGRP(E, G) do {                                                    \
    if (8 * (G) + 8 <= total) { RUN8(E); }                                   \
    else { RUN8G(E, total - 8 * (G)); }                                      \
    APPLY(); MEASURE();                                                      \
  } while (0)

    POLL(3);
    LD8(e, 0);
    if (1 < ng) LD8(f, 1);
    if (2 < ng) LD8(g, 2);
    int cg = 0;
    for (;;) {
      POLL(min(cg + 6, ng));
      RUNGRP(e, cg);
      if (cg + 3 < ng) LD8(e, cg + 3);
      if (cg + 1 < ng) {
        RUNGRP(f, cg + 1);
        if (cg + 4 < ng) LD8(f, cg + 4);
      }
      if (cg + 2 < ng) {
        RUNGRP(g, cg + 2);
        if (cg + 5 < ng) LD8(g, cg + 5);
      }
      __asm__ __volatile__("" ::: "memory");
      if (lane == 0) *(volatile int*)&consG = cg + 6;   // after LD8s (in-order DS)
      cg += 3;
      if (cg >= ng) break;
    }
#undef POLL
#undef LD8
#undef STEP1
#undef STEP1G
#undef RUN8
#undef RUN8G
#undef APPLY
#undef MEASURE
#undef RUNGRP

    // readout: a_last = state 2*kl, a_prev = state 2*kl-1
    float* ev = (float*)ring;
    float* od = (float*)(ring + 4096);
    *(float4*)(ev + (lane << 2)) = make_float4(a0, a1, a2, a3);
    *(float4*)(od + (lane << 2)) = make_float4(b0, b1, b2, b3);
    if (lane == 63) *(float*)(ring + 8192) = s512;
    __asm__ __volatile__("" ::: "memory");
    if (lane == 0) {
      const float aL = (kl < 256) ? ev[kl] : *(float*)(ring + 8192);
      const float aP = od[kl - 1];
      const float dC = (float)Cw - (float)total * LOG2E;  // e-fold removal
      alast[b] = (log2f(aL) + dC) * LN2f;
      aprev[b] = (log2f(aP) + dC) * LN2f;
    }
  } else {
    // =================== producers: waves 1..3 ===================
    const int pw = w - 1;                    // handles groups g % 3 == pw
    const int c0 = lane << 2;
    const float bs0 = (c0 + 0 < kl) ? LOG2E : -20000.f;
    const float bs1 = (c0 + 1 < kl) ? LOG2E : -20000.f;
    const float bs2 = (c0 + 2 < kl) ? LOG2E : -20000.f;
    const float bs3 = (c0 + 3 < kl) ? LOG2E : -20000.f;
    volatile int* vc = &consG;
    float acc = 0.f;                         // row-lse partial (log2 units)

    if (pw == 0) {                           // row 0: lse only (not staged)
      const float4 v = *(const float4*)(xbc + lane16);
      float s_ = __builtin_amdgcn_exp2f(fmaf(v.x, LOG2E, bs0))
               + __builtin_amdgcn_exp2f(fmaf(v.y, LOG2E, bs1))
               + __builtin_amdgcn_exp2f(fmaf(v.z, LOG2E, bs2))
               + __builtin_amdgcn_exp2f(fmaf(v.w, LOG2E, bs3));
      s_ = dsum64(s_);
      acc += __builtin_amdgcn_logf((s_ + 1.0f) * WBF);
    }

    float4 A0, A1, A2, A3, A4, A5, A6, A7;
    float4 B0, B1, B2, B3, B4, B5, B6, B7;
    float4 C0, C1, C2, C3, C4, C5, C6, C7;

#define LOADG(P, GG) do {                                                    \
    const int rb_ = 8 * (GG) + 1;                                            \
    P##0 = *(const float4*)(xbc + (size_t)min(rb_ + 0, TB - 1) * 1024 + lane16); \
    P##1 = *(const float4*)(xbc + (size_t)min(rb_ + 1, TB - 1) * 1024 + lane16); \
    P##2 = *(const float4*)(xbc + (size_t)min(rb_ + 2, TB - 1) * 1024 + lane16); \
    P##3 = *(const float4*)(xbc + (size_t)min(rb_ + 3, TB - 1) * 1024 + lane16); \
    P##4 = *(const float4*)(xbc + (size_t)min(rb_ + 4, TB - 1) * 1024 + lane16); \
    P##5 = *(const float4*)(xbc + (size_t)min(rb_ + 5, TB - 1) * 1024 + lane16); \
    P##6 = *(const float4*)(xbc + (size_t)min(rb_ + 6, TB - 1) * 1024 + lane16); \
    P##7 = *(const float4*)(xbc + (size_t)min(rb_ + 7, TB - 1) * 1024 + lane16); \
  } while (0)

#define PR1(V, J) do {                                                       \
    float4 wv_;                                                              \
    wv_.x = __builtin_amdgcn_exp2f(fmaf(V.x, LOG2E, bs0));                   \
    wv_.y = __builtin_amdgcn_exp2f(fmaf(V.y, LOG2E, bs1));                   \
    wv_.z = __builtin_amdgcn_exp2f(fmaf(V.z, LOG2E, bs2));                   \
    wv_.w = __builtin_amdgcn_exp2f(fmaf(V.w, LOG2E, bs3));                   \
    *(float4*)(dstb_ + ((J) << 10)) = wv_;                                   \
    if (rb_ + (J) <= total) {                                                \
      float sr_ = (wv_.x + wv_.y) + (wv_.z + wv_.w);                         \
      sr_ = dsum64(sr_);                                                     \
      acc += __builtin_amdgcn_logf((sr_ + 1.0f) * WBF);                      \
    }                                                                        \
  } while (0)

#define PROC(P, GG) do {                                                     \
    const int rb_ = 8 * (GG) + 1;                                            \
    if ((GG) >= 8) {                        /* ring slot reuse */            \
      int c_ = *vc;                                                          \
      while (c_ < (GG) - 7) { __builtin_amdgcn_s_sleep(2); c_ = *vc; }       \
      __asm__ __volatile__("" ::: "memory");                                 \
    }                                                                        \
    char* dstb_ = ring + (((GG) & 7) << 13) + lane16;                        \
    PR1(P##0, 0); PR1(P##1, 1); PR1(P##2, 2); PR1(P##3, 3);                  \
    PR1(P##4, 4); PR1(P##5, 5); PR1(P##6, 6); PR1(P##7, 7);                  \
    __asm__ __volatile__("s_waitcnt lgkmcnt(0)" ::: "memory");               \
    if (lane == 0) *(volatile int*)&prodG[pw] = (GG) + 3;                    \
  } while (0)

    LOADG(A, pw); LOADG(B, pw + 3);
    int g = pw;
    for (;;) {
      LOADG(C, g + 6);
      PROC(A, g);
      g += 3; if (g >= ng) break;
      LOADG(A, g + 6);
      PROC(B, g);
      g += 3; if (g >= ng) break;
      LOADG(B, g + 6);
      PROC(C, g);
      g += 3; if (g >= ng) break;
    }
#undef LOADG
#undef PR1
#undef PROC
    __asm__ __volatile__("" ::: "memory");
    if (lane == 0) *(volatile int*)&prodG[pw] = 0x7fffffff;
    if (lane == 63) partial[4 * b + pw] = acc;   // log2-units partial
  }
}

// ---------------------------------------------------------------------------
// finish: per-batch SumLse + loss + mean. One wave of 64 threads.
// ---------------------------------------------------------------------------
__global__ __launch_bounds__(64)
void fsl_finish(const float* __restrict__ partial, const int* __restrict__ key_lens,
                const float* __restrict__ alast, const float* __restrict__ aprev,
                float* __restrict__ out) {
  const int b = threadIdx.x;                 // 0..63
  const float SumLse =
      ((partial[4 * b] + partial[4 * b + 1]) + partial[4 * b + 2]) * LN2f;
  const float al = alast[b], ap = aprev[b];
  const float mx = fmaxf(al, ap);
  const float lae = (mx == -INFINITY) ? -INFINITY
                                      : mx + log1pf(expf(-fabsf(al - ap)));
  const float nll = SumLse - lae;
  const int kl = key_lens[b];
  float lv = nll / (float)max(kl, 1);
  if (nll > 5e29f) lv = 0.f;
  float v = wsum64(lv);
  if (b == 0) out[0] = v * (1.0f / 64.0f);
}

extern "C" void kernel_launch(void* const* d_in, const int* in_sizes, int n_in,
                              void* d_out, int out_size, void* d_ws, size_t ws_size,
                              hipStream_t stream) {
  const float* x     = (const float*)d_in[0];
  const int*   klens = (const int*)d_in[1];
  const int*   qlens = (const int*)d_in[2];
  float* out = (float*)d_out;

  float* partial = (float*)d_ws;            // 64*4 floats (3 used per batch)
  float* alast   = partial + BB * 4;        // 64
  float* aprev   = alast + BB;              // 64

  fsl_main  <<<BB, 256, 0, stream>>>(x, klens, qlens, partial, alast, aprev);
  fsl_finish<<<1, 64, 0, stream>>>(partial, klens, alast, aprev, out);
}

// Round 10
// 119.736 us; speedup vs baseline: 1.8342x; 1.0355x over previous
//
#include <hip/hip_runtime.h>
#include <cstdint>
#include <cstddef>

// Problem constants (match reference)
#define BB    64
#define TB    2000
#define KB    256

constexpr float LOG2E = 1.4426950408889634f;
constexpr float LN2f  = 0.6931471805599453f;
constexpr float WBF   = 0.36787944117144233f;   // exp(-1)

__device__ __forceinline__ float exp2i(int k) {  // exact 2^k, k in [-126,127]
  return __uint_as_float((uint32_t)(127 + k) << 23);
}
// lane i <- lane i-1 (lane 0 <- 0): DPP wave_shr:1, pure VALU (validated r4-r9)
__device__ __forceinline__ float shr1z(float v) {
  return __int_as_float(__builtin_amdgcn_update_dpp(
      0, __float_as_int(v), 0x138, 0xF, 0xF, true));
}
// wave64 max, pure-VALU DPP tree (validated r6-r9); uniform via readlane(63)
__device__ __forceinline__ float dmax64(float v) {
#define DSTEP(ctrl, rm, bc)                                                  \
  { float t = __int_as_float(__builtin_amdgcn_update_dpp(                    \
        __float_as_int(v), __float_as_int(v), (ctrl), (rm), 0xF, (bc)));     \
    v = fmaxf(v, t); }
  DSTEP(0x111, 0xF, true) DSTEP(0x112, 0xF, true) DSTEP(0x114, 0xF, true)
  DSTEP(0x118, 0xF, true) DSTEP(0x142, 0xA, false) DSTEP(0x143, 0xC, false)
#undef DSTEP
  return __int_as_float(__builtin_amdgcn_readlane(__float_as_int(v), 63));
}
// wave64 sum, pure-VALU DPP tree; total valid in lane 63 (validated r6-r9)
__device__ __forceinline__ float dsum64(float v) {
#define DSTEP(ctrl, rm, bc)                                                  \
  { float t = __int_as_float(__builtin_amdgcn_update_dpp(                    \
        __float_as_int(v), __float_as_int(v), (ctrl), (rm), 0xF, (bc)));     \
    v += t; }
  DSTEP(0x111, 0xF, true) DSTEP(0x112, 0xF, true) DSTEP(0x114, 0xF, true)
  DSTEP(0x118, 0xF, true) DSTEP(0x142, 0xA, false) DSTEP(0x143, 0xC, false)
#undef DSTEP
  return v;
}
__device__ __forceinline__ float wsum64(float v) {
#pragma unroll
  for (int m = 32; m >= 1; m >>= 1) v += __shfl_xor(v, m, 64);
  return v;
}

// ---------------------------------------------------------------------------
// 64 blocks, one per batch. Wave 0 = consumer scan (513 states, 4 pairs/lane,
// 1 DPP shift/step, zero transcendentals, zero barriers). Waves 1-3 =
// producers: compute weight rows w = exp2(x*log2e + bias) (bias bakes
// key-mask + e^1-fold), ds_write into an 8-group LDS ring, and fold the row
// log-sum-exp from the same exp2s. Single pass over x.
// r10 deltas vs r9: __launch_bounds__(256,1) so the 96-VGPR group triple
// buffer stays RESIDENT (r9's 88-VGPR allocation demoted it, re-exposing LDS
// latency per group); consumer loop split into unguarded main + guarded tail.
// Flag protocol proven r7-r9: per-wave in-order DS retirement orders
// data-write -> flag-write and data-read -> consG-write.
// ---------------------------------------------------------------------------
__global__ __launch_bounds__(256, 1)
void fsl_main(const float* __restrict__ x, const int* __restrict__ key_lens,
              const int* __restrict__ query_lens, float* __restrict__ partial,
              float* __restrict__ alast, float* __restrict__ aprev) {
  __shared__ __align__(16) char ring[65536];   // 8 groups x 8 rows x 1KB
  __shared__ __align__(16) int prodG[4];       // 3 flags + pad (one b128 read)
  __shared__ int consG;

  const int tid  = threadIdx.x;
  const int b    = blockIdx.x;
  const int lane = tid & 63;
  const int w    = tid >> 6;
  const int kl   = key_lens[b];
  const int qlen = query_lens[b];
  const int total = qlen - 1;                // live steps t = 1..total
  const int ng    = (total + 7) >> 3;        // 8-step groups (>=125)
  const float* xb  = x + (size_t)b * (TB * KB);
  const char*  xbc = (const char*)xb;
  const int lane16 = lane << 4;

  if (tid == 0) { prodG[0] = 0; prodG[1] = 0; prodG[2] = 0; prodG[3] = 0x7fffffff; consG = 0; }
  __syncthreads();                           // the ONLY barrier

  if (w == 0) {
    // =================== consumer: the scan wave ===================
    float a0 = 0.f, a1 = 0.f, a2 = 0.f, a3 = 0.f;
    float b0 = 0.f, b1 = 0.f, b2 = 0.f, b3 = 0.f, s512 = 0.f;
    if (lane == 0) { a0 = WBF; b0 = __builtin_amdgcn_exp2f(xb[0] * LOG2E); }
    int Cw = 0;
    float m_red = dmax64(fmaxf(a0, b0));

    float4 e0, e1, e2, e3, e4, e5, e6, e7;
    float4 f0, f1, f2, f3, f4, f5, f6, f7;
    float4 g0, g1, g2, g3, g4, g5, g6, g7;

    // one ds_read_b128 of all 3 flags; spin first, sleep(1) after
#define POLL(GN) do {                                                        \
    const int tgt_ = (GN);                                                   \
    for (;;) {                                                               \
      __asm__ __volatile__("" ::: "memory");                                 \
      const int4 fl_ = *(const int4*)prodG;                                  \
      if (min(fl_.x, min(fl_.y, fl_.z)) >= tgt_) break;                      \
      __builtin_amdgcn_s_sleep(1);                                           \
    }                                                                        \
    __asm__ __volatile__("" ::: "memory");                                   \
  } while (0)

#define LD8(E, g) do {                                                       \
    const char* sb_ = ring + (((g) & 7) << 13) + lane16;                     \
    E##0 = *(const float4*)(sb_);                                            \
    E##1 = *(const float4*)(sb_ + 1024);                                     \
    E##2 = *(const float4*)(sb_ + 2048);                                     \
    E##3 = *(const float4*)(sb_ + 3072);                                     \
    E##4 = *(const float4*)(sb_ + 4096);                                     \
    E##5 = *(const float4*)(sb_ + 5120);                                     \
    E##6 = *(const float4*)(sb_ + 6144);                                     \
    E##7 = *(const float4*)(sb_ + 7168);                                     \
  } while (0)

    // EV holds the PRECOMPUTED weights for this step (4 odd-state weights)
#define STEP1(EV) do {                                                       \
    const float pm1 = shr1z(b3);                                             \
    const float t0_ = a0 + pm1;                                              \
    const float t1_ = a1 + b0;                                               \
    const float t2_ = a2 + b1;                                               \
    const float t3_ = a3 + b2;                                               \
    s512 = s512 + b3;                                                        \
    b0 = (b0 + t0_) * EV.x;                                                  \
    b1 = (b1 + t1_) * EV.y;                                                  \
    b2 = (b2 + t2_) * EV.z;                                                  \
    b3 = (b3 + t3_) * EV.w;                                                  \
    a0 = t0_; a1 = t1_; a2 = t2_; a3 = t3_;                                  \
  } while (0)

#define STEP1G(EV, J) do { if ((J) < rem_) { STEP1(EV); } } while (0)

#define RUN8(E)  do { STEP1(E##0); STEP1(E##1); STEP1(E##2); STEP1(E##3);    \
                      STEP1(E##4); STEP1(E##5); STEP1(E##6); STEP1(E##7); } while (0)
#define RUN8G(E, RM) do { const int rem_ = (RM);                             \
                      STEP1G(E##0,0); STEP1G(E##1,1); STEP1G(E##2,2);        \
                      STEP1G(E##3,3); STEP1G(E##4,4); STEP1G(E##5,5);        \
                      STEP1G(E##6,6); STEP1G(E##7,7); } while (0)

#define APPLY() do {                                                         \
    int e_ = (int)((__float_as_uint(m_red) >> 23) & 0xFF) - 127;             \
    if (!(m_red > 0.f)) e_ = -24;                                            \
    const int k_ = e_ + 24;              /* normalize max to 2^-24 */        \
    if (k_ > 126) {                                                          \
      const int kh_ = k_ >> 1;                                               \
      const float s1_ = exp2i(-kh_), s2_ = exp2i(-(k_ - kh_));               \
      a0 *= s1_; a1 *= s1_; a2 *= s1_; a3 *= s1_;                            \
      b0 *= s1_; b1 *= s1_; b2 *= s1_; b3 *= s1_; s512 *= s1_;               \
      a0 *= s2_; a1 *= s2_; a2 *= s2_; a3 *= s2_;                            \
      b0 *= s2_; b1 *= s2_; b2 *= s2_; b3 *= s2_; s512 *= s2_;               \
    } else {                                                                 \
      const float s_ = exp2i(-k_);                                           \
      a0 *= s_; a1 *= s_; a2 *= s_; a3 *= s_;                                \
      b0 *= s_; b1 *= s_; b2 *= s_; b3 *= s_; s512 *= s_;                    \
    }                                                                        \
    Cw += k_;                                                                \
  } while (0)

#define MEASURE() do {                                                       \
    float ml_ = fmaxf(fmaxf(fmaxf(a0, a1), fmaxf(a2, a3)),                   \
                      fmaxf(fmaxf(b0, b1), fmaxf(b2, b3)));                  \
    ml_ = fmaxf(ml_, s512);                                                  \
    m_red = dmax64(ml_);                                                     \
  } while (0)

#define RUNGRP(E, G) do {                                                    \
    if (8 * (G) + 8 <= total) { RUN8(E); }                                   \
    else { RUN8G(E, total - 8 * (G)); }                                      \
    APPLY(); MEASURE();                                                      \
  } while (0)

    POLL(3);
    LD8(e, 0);
    if (1 < ng) LD8(f, 1);
    if (2 < ng) LD8(g, 2);
    int cg = 0;
    // -------- main loop: fully-live groups, prefetch always valid --------
    while (cg + 6 <= ng && 8 * (cg + 3) <= total) {
      POLL(cg + 6);
      RUN8(e); APPLY(); MEASURE(); LD8(e, cg + 3);
      RUN8(f); APPLY(); MEASURE(); LD8(f, cg + 4);
      RUN8(g); APPLY(); MEASURE(); LD8(g, cg + 5);
      __asm__ __volatile__("" ::: "memory");
      if (lane == 0) *(volatile int*)&consG = cg + 6;   // after LD8s (in-order DS)
      cg += 3;
    }
    // -------- guarded tail --------
    for (; cg < ng; cg += 3) {
      POLL(min(cg + 6, ng));
      RUNGRP(e, cg);
      if (cg + 3 < ng) LD8(e, cg + 3);
      if (cg + 1 < ng) {
        RUNGRP(f, cg + 1);
        if (cg + 4 < ng) LD8(f, cg + 4);
      }
      if (cg + 2 < ng) {
        RUNGRP(g, cg + 2);
        if (cg + 5 < ng) LD8(g, cg + 5);
      }
      __asm__ __volatile__("" ::: "memory");
      if (lane == 0) *(volatile int*)&consG = cg + 6;
    }
#undef POLL
#undef LD8
#undef STEP1
#undef STEP1G
#undef RUN8
#undef RUN8G
#undef APPLY
#undef MEASURE
#undef RUNGRP

    // readout: a_last = state 2*kl, a_prev = state 2*kl-1
    float* ev = (float*)ring;
    float* od = (float*)(ring + 4096);
    *(float4*)(ev + (lane << 2)) = make_float4(a0, a1, a2, a3);
    *(float4*)(od + (lane << 2)) = make_float4(b0, b1, b2, b3);
    if (lane == 63) *(float*)(ring + 8192) = s512;
    __asm__ __volatile__("" ::: "memory");
    if (lane == 0) {
      const float aL = (kl < 256) ? ev[kl] : *(float*)(ring + 8192);
      const float aP = od[kl - 1];
      const float dC = (float)Cw - (float)total * LOG2E;  // e-fold removal
      alast[b] = (log2f(aL) + dC) * LN2f;
      aprev[b] = (log2f(aP) + dC) * LN2f;
    }
  } else {
    // =================== producers: waves 1..3 ===================
    const int pw = w - 1;                    // handles groups g % 3 == pw
    const int c0 = lane << 2;
    const float bs0 = (c0 + 0 < kl) ? LOG2E : -20000.f;
    const float bs1 = (c0 + 1 < kl) ? LOG2E : -20000.f;
    const float bs2 = (c0 + 2 < kl) ? LOG2E : -20000.f;
    const float bs3 = (c0 + 3 < kl) ? LOG2E : -20000.f;
    volatile int* vc = &consG;
    float acc = 0.f;                         // row-lse partial (log2 units)

    if (pw == 0) {                           // row 0: lse only (not staged)
      const float4 v = *(const float4*)(xbc + lane16);
      float s_ = __builtin_amdgcn_exp2f(fmaf(v.x, LOG2E, bs0))
               + __builtin_amdgcn_exp2f(fmaf(v.y, LOG2E, bs1))
               + __builtin_amdgcn_exp2f(fmaf(v.z, LOG2E, bs2))
               + __builtin_amdgcn_exp2f(fmaf(v.w, LOG2E, bs3));
      s_ = dsum64(s_);
      acc += __builtin_amdgcn_logf((s_ + 1.0f) * WBF);
    }

    float4 A0, A1, A2, A3, A4, A5, A6, A7;
    float4 B0, B1, B2, B3, B4, B5, B6, B7;
    float4 C0, C1, C2, C3, C4, C5, C6, C7;

#define LOADG(P, GG) do {                                                    \
    const int rb_ = 8 * (GG) + 1;                                            \
    P##0 = *(const float4*)(xbc + (size_t)min(rb_ + 0, TB - 1) * 1024 + lane16); \
    P##1 = *(const float4*)(xbc + (size_t)min(rb_ + 1, TB - 1) * 1024 + lane16); \
    P##2 = *(const float4*)(xbc + (size_t)min(rb_ + 2, TB - 1) * 1024 + lane16); \
    P##3 = *(const float4*)(xbc + (size_t)min(rb_ + 3, TB - 1) * 1024 + lane16); \
    P##4 = *(const float4*)(xbc + (size_t)min(rb_ + 4, TB - 1) * 1024 + lane16); \
    P##5 = *(const float4*)(xbc + (size_t)min(rb_ + 5, TB - 1) * 1024 + lane16); \
    P##6 = *(const float4*)(xbc + (size_t)min(rb_ + 6, TB - 1) * 1024 + lane16); \
    P##7 = *(const float4*)(xbc + (size_t)min(rb_ + 7, TB - 1) * 1024 + lane16); \
  } while (0)

#define PR1(V, J) do {                                                       \
    float4 wv_;                                                              \
    wv_.x = __builtin_amdgcn_exp2f(fmaf(V.x, LOG2E, bs0));                   \
    wv_.y = __builtin_amdgcn_exp2f(fmaf(V.y, LOG2E, bs1));                   \
    wv_.z = __builtin_amdgcn_exp2f(fmaf(V.z, LOG2E, bs2));                   \
    wv_.w = __builtin_amdgcn_exp2f(fmaf(V.w, LOG2E, bs3));                   \
    *(float4*)(dstb_ + ((J) << 10)) = wv_;                                   \
    if (rb_ + (J) <= total) {                                                \
      float sr_ = (wv_.x + wv_.y) + (wv_.z + wv_.w);                         \
      sr_ = dsum64(sr_);                                                     \
      acc += __builtin_amdgcn_logf((sr_ + 1.0f) * WBF);                      \
    }                                                                        \
  } while (0)

#define PROC(P, GG) do {                                                     \
    const int rb_ = 8 * (GG) + 1;                                            \
    if ((GG) >= 8) {                        /* ring slot reuse */            \
      int c_ = *vc;                                                          \
      while (c_ < (GG) - 7) { __builtin_amdgcn_s_sleep(2); c_ = *vc; }       \
      __asm__ __volatile__("" ::: "memory");                                 \
    }                                                                        \
    char* dstb_ = ring + (((GG) & 7) << 13) + lane16;                        \
    PR1(P##0, 0); PR1(P##1, 1); PR1(P##2, 2); PR1(P##3, 3);                  \
    PR1(P##4, 4); PR1(P##5, 5); PR1(P##6, 6); PR1(P##7, 7);                  \
    __asm__ __volatile__("s_waitcnt lgkmcnt(0)" ::: "memory");               \
    if (lane == 0) *(volatile int*)&prodG[pw] = (GG) + 3;                    \
  } while (0)

    LOADG(A, pw); LOADG(B, pw + 3);
    int g = pw;
    for (;;) {
      LOADG(C, g + 6);
      PROC(A, g);
      g += 3; if (g >= ng) break;
      LOADG(A, g + 6);
      PROC(B, g);
      g += 3; if (g >= ng) break;
      LOADG(B, g + 6);
      PROC(C, g);
      g += 3; if (g >= ng) break;
    }
#undef LOADG
#undef PR1
#undef PROC
    __asm__ __volatile__("" ::: "memory");
    if (lane == 0) *(volatile int*)&prodG[pw] = 0x7fffffff;
    if (lane == 63) partial[4 * b + pw] = acc;   // log2-units partial
  }
}

// ---------------------------------------------------------------------------
// finish: per-batch SumLse + loss + mean. One wave of 64 threads.
// ---------------------------------------------------------------------------
__global__ __launch_bounds__(64)
void fsl_finish(const float* __restrict__ partial, const int* __restrict__ key_lens,
                const float* __restrict__ alast, const float* __restrict__ aprev,
                float* __restrict__ out) {
  const int b = threadIdx.x;                 // 0..63
  const float SumLse =
      ((partial[4 * b] + partial[4 * b + 1]) + partial[4 * b + 2]) * LN2f;
  const float al = alast[b], ap = aprev[b];
  const float mx = fmaxf(al, ap);
  const float lae = (mx == -INFINITY) ? -INFINITY
                                      : mx + log1pf(expf(-fabsf(al - ap)));
  const float nll = SumLse - lae;
  const int kl = key_lens[b];
  float lv = nll / (float)max(kl, 1);
  if (nll > 5e29f) lv = 0.f;
  float v = wsum64(lv);
  if (b == 0) out[0] = v * (1.0f / 64.0f);
}

extern "C" void kernel_launch(void* const* d_in, const int* in_sizes, int n_in,
                              void* d_out, int out_size, void* d_ws, size_t ws_size,
                              hipStream_t stream) {
  const float* x     = (const float*)d_in[0];
  const int*   klens = (const int*)d_in[1];
  const int*   qlens = (const int*)d_in[2];
  float* out = (float*)d_out;

  float* partial = (float*)d_ws;            // 64*4 floats (3 used per batch)
  float* alast   = partial + BB * 4;        // 64
  float* aprev   = alast + BB;              // 64

  fsl_main  <<<BB, 256, 0, stream>>>(x, klens, qlens, partial, alast, aprev);
  fsl_finish<<<1, 64, 0, stream>>>(partial, klens, alast, aprev, out);
}